// Round 15
// baseline (125.767 us; speedup 1.0000x reference)
//
#include <hip/hip_runtime.h>
#include <cstdint>

// Transformer block: B=16, S=1024, E=256, H=4, D=64. fp32 in/out, bf16 compute.
// T = B*S = 16384 tokens.
//
//  0. prep  = wconv(all weights) + LN1(x)      -> ws (one kernel)
//  1. qkv   = h @ qkv_w + qkv_b         bf16   -> qk_buf [T,512] + vt_buf [BH,64,1024]
//             (q columns pre-scaled by 1/sqrt(D)*log2e)
//  2. o     = causal_attn(qk, vt)       bf16   -> bufA   (32x32 MFMA, QBLK=128,
//             KVBLK=128 dbuf staged, V-prefetch, diagonal-tile skip: on the
//             last kv-tile, wave w computes only jt<=w (others fully masked))
//  3. x1,h2 = fused(x + o@out_w+b, LN2) f32,bf16 -> d_out, bufA   (dbuf)
//  4. h3    = relu(h2 @ fc_w + b)       bf16   -> h3_buf
//  5. out   = x1 + h3 @ proj_w + b      fp32   -> d_out           (dbuf)

using f32x4  = __attribute__((ext_vector_type(4))) float;
using f32x16 = __attribute__((ext_vector_type(16))) float;
using s16x8  = __attribute__((ext_vector_type(8))) short;
using s16x4  = __attribute__((ext_vector_type(4))) short;

__device__ inline short f2bf(float f) {
    union { float f; unsigned u; } v{f};
    unsigned r = (v.u + 0x7FFFu + ((v.u >> 16) & 1u)) >> 16;   // RNE
    return (short)r;
}

__device__ inline int cvt_pk_bf16(float lo, float hi) {
    int d;
    asm("v_cvt_pk_bf16_f32 %0, %1, %2" : "=v"(d) : "v"(lo), "v"(hi));
    return d;
}
__device__ inline void swap32(int& a, int& b) {
    asm("v_permlane32_swap_b32 %0, %1" : "+v"(a), "+v"(b));
}
__device__ inline void swap16(int& a, int& b) {
    asm("v_permlane16_swap_b32 %0, %1" : "+v"(a), "+v"(b));
}

__device__ inline void gload16(const void* g, void* l) {
    __builtin_amdgcn_global_load_lds(
        (const __attribute__((address_space(1))) void*)g,
        (__attribute__((address_space(3))) void*)l, 16, 0, 0);
}

// ------------------------------------------------ prep: weight conv + LN1
__global__ __launch_bounds__(256) void prep_kernel(
    const float* __restrict__ qkv_w, const float* __restrict__ out_w,
    const float* __restrict__ fc_w,  const float* __restrict__ proj_w,
    short* __restrict__ wt_qkv, short* __restrict__ wt_out,
    short* __restrict__ wt_fc,  short* __restrict__ wt_proj,
    const float* __restrict__ x, const float* __restrict__ ln1_g,
    const float* __restrict__ ln1_b, short* __restrict__ hout)
{
    __shared__ short T[64][65];
    int id  = blockIdx.x;
    int tid = threadIdx.x;

    if (id < 192) {
        const float* W; short* Wt; int K, N, nt, kt;
        if (id < 48)       { W = qkv_w;  Wt = wt_qkv;  K = 256;  N = 768;  nt = id % 12;        kt = id / 12; }
        else if (id < 64)  { W = out_w;  Wt = wt_out;  K = 256;  N = 256;  nt = (id - 48) & 3;  kt = (id - 48) >> 2; }
        else if (id < 128) { W = fc_w;   Wt = wt_fc;   K = 256;  N = 1024; nt = (id - 64) & 15; kt = (id - 64) >> 4; }
        else               { W = proj_w; Wt = wt_proj; K = 1024; N = 256;  nt = (id - 128) & 3; kt = (id - 128) >> 2; }
        int n0 = nt * 64, k0 = kt * 64;
        int r = tid >> 2, c = (tid & 3) << 4;
        const float* src = W + (size_t)(k0 + r) * N + n0 + c;
#pragma unroll
        for (int u = 0; u < 4; ++u) {
            float4 v = *reinterpret_cast<const float4*>(src + u * 4);
            T[r][c + u * 4 + 0] = f2bf(v.x);
            T[r][c + u * 4 + 1] = f2bf(v.y);
            T[r][c + u * 4 + 2] = f2bf(v.z);
            T[r][c + u * 4 + 3] = f2bf(v.w);
        }
        __syncthreads();
        s16x8 o0, o1;
#pragma unroll
        for (int jj = 0; jj < 8; ++jj) { o0[jj] = T[c + jj][r]; o1[jj] = T[c + 8 + jj][r]; }
        short* dst = Wt + (size_t)(n0 + r) * K + k0 + c;
        *reinterpret_cast<s16x8*>(dst)     = o0;
        *reinterpret_cast<s16x8*>(dst + 8) = o1;
    } else {
        int lane = tid & 63;
        int row  = (id - 192) * 4 + (tid >> 6);
        const float* xr = x + (size_t)row * 256;
        float4 v = *reinterpret_cast<const float4*>(xr + lane * 4);
        float s = v.x + v.y + v.z + v.w;
#pragma unroll
        for (int o2 = 32; o2 >= 1; o2 >>= 1) s += __shfl_xor(s, o2);
        float mu = s * (1.0f / 256.0f);
        float dx = v.x - mu, dy = v.y - mu, dz = v.z - mu, dw = v.w - mu;
        float q = dx * dx + dy * dy + dz * dz + dw * dw;
#pragma unroll
        for (int o2 = 32; o2 >= 1; o2 >>= 1) q += __shfl_xor(q, o2);
        float rstd = rsqrtf(q * (1.0f / 256.0f) + 1e-5f);
        float4 gv = *reinterpret_cast<const float4*>(ln1_g + lane * 4);
        float4 bv = *reinterpret_cast<const float4*>(ln1_b + lane * 4);
        s16x4 ov;
        ov[0] = f2bf(dx * rstd * gv.x + bv.x);
        ov[1] = f2bf(dy * rstd * gv.y + bv.y);
        ov[2] = f2bf(dz * rstd * gv.z + bv.z);
        ov[3] = f2bf(dw * rstd * gv.w + bv.w);
        *reinterpret_cast<s16x4*>(hout + (size_t)row * 256 + lane * 4) = ov;
    }
}

// ---------------------------------------------------------------- MFMA GEMM (qkv)
template <int BM>
__global__ __launch_bounds__(256) void qkv_gemm_kernel(const short* __restrict__ A,
                                                       const short* __restrict__ Bt,
                                                       const float* __restrict__ bias,
                                                       short* __restrict__ qkout,
                                                       short* __restrict__ vt,
                                                       int N, int K)
{
    constexpr int MI = BM / 32;
    __shared__ short As[BM * 64];
    __shared__ short Bs[128 * 64];

    int tid = threadIdx.x;
    int l   = tid & 63;
    int w   = tid >> 6;
    int lr  = l & 15;
    int lk8 = (l >> 4) << 3;
    int r4  = (l >> 4) << 2;
    int wr  = w >> 1, wc = w & 1;
    int bn  = blockIdx.x * 128, bm = blockIdx.y * BM;

    int scolS = ((l & 7) << 3) ^ ((l >> 3) << 3);
    int srowA = w * (BM / 4) + (l >> 3);
    int srowB = (w << 5) + (l >> 3);
    const short* pa = A  + (size_t)(bm + srowA) * K + scolS;
    const short* pb = Bt + (size_t)(bn + srowB) * K + scolS;
    short* dstA = As + w * (BM / 4) * 64;
    short* dstB = Bs + (w << 11);

    f32x4 acc[MI][4];
#pragma unroll
    for (int mi = 0; mi < MI; ++mi)
#pragma unroll
        for (int ni = 0; ni < 4; ++ni) acc[mi][ni] = (f32x4){0.f, 0.f, 0.f, 0.f};

    int swz = (lr & 7) << 3;

    for (int k0 = 0; k0 < K; k0 += 64) {
        __syncthreads();
#pragma unroll
        for (int i = 0; i < BM / 32; ++i)
            gload16(pa + (size_t)(i * 8) * K + k0, dstA + (i << 9));
#pragma unroll
        for (int i = 0; i < 4; ++i)
            gload16(pb + (size_t)(i * 8) * K + k0, dstB + (i << 9));
        __syncthreads();

#pragma unroll
        for (int ks = 0; ks < 2; ++ks) {
            s16x8 af[MI], bf[4];
#pragma unroll
            for (int mi = 0; mi < MI; ++mi) {
                int row = wr * (BM / 2) + (mi << 4) + lr;
                af[mi] = *reinterpret_cast<const s16x8*>(
                    &As[(row << 6) + (((ks << 5) + lk8) ^ swz)]);
            }
#pragma unroll
            for (int ni = 0; ni < 4; ++ni) {
                int row = (wc << 6) + (ni << 4) + lr;
                bf[ni] = *reinterpret_cast<const s16x8*>(
                    &Bs[(row << 6) + (((ks << 5) + lk8) ^ swz)]);
            }
            __builtin_amdgcn_s_setprio(1);
#pragma unroll
            for (int mi = 0; mi < MI; ++mi)
#pragma unroll
                for (int ni = 0; ni < 4; ++ni)
                    acc[mi][ni] = __builtin_amdgcn_mfma_f32_16x16x32_bf16(
                        af[mi], bf[ni], acc[mi][ni], 0, 0, 0);
            __builtin_amdgcn_s_setprio(0);
        }
    }

    const float SCQ = 0.125f * 1.44269504088896f;   // 1/sqrt(D) * log2(e)
    float scale = (bn < 256) ? SCQ : 1.0f;          // block-uniform

    float bv[4];
#pragma unroll
    for (int ni = 0; ni < 4; ++ni)
        bv[ni] = bias[bn + (wc << 6) + (ni << 4) + lr];

#pragma unroll
    for (int mi = 0; mi < MI; ++mi) {
#pragma unroll
        for (int ni = 0; ni < 4; ++ni) {
            int n = bn + (wc << 6) + (ni << 4) + lr;
#pragma unroll
            for (int r = 0; r < 4; ++r) {
                int m = bm + wr * (BM / 2) + (mi << 4) + r4 + r;
                float v = acc[mi][ni][r] + bv[ni];
                if (bn < 512) {
                    qkout[(size_t)m * 512 + n] = f2bf(v * scale);
                } else {
                    int hh = (n - 512) >> 6, dd = (n - 512) & 63;
                    int bb = m >> 10, ss = m & 1023;
                    vt[(size_t)((((bb << 2) | hh) << 6) | dd) * 1024 + ss] = f2bf(v);
                }
            }
        }
    }
}

// ---------------------------------------------------------------- MFMA GEMM
template <int RELU, int RES, int OBF16, int BM, int DBUF>
__global__ __launch_bounds__(256) void mgemm_kernel(const short* __restrict__ A,
                                                    const short* __restrict__ Bt,
                                                    const float* __restrict__ bias,
                                                    const float* __restrict__ R,
                                                    void* __restrict__ Cv,
                                                    int N, int K)
{
    constexpr int MI  = BM / 32;
    constexpr int ASZ = BM * 64;
    constexpr int BSZ = 128 * 64;
    __shared__ short As[(1 + DBUF) * ASZ];
    __shared__ short Bs[(1 + DBUF) * BSZ];

    int tid = threadIdx.x;
    int l   = tid & 63;
    int w   = tid >> 6;
    int lr  = l & 15;
    int lk8 = (l >> 4) << 3;
    int r4  = (l >> 4) << 2;
    int wr  = w >> 1, wc = w & 1;
    int bn  = blockIdx.x * 128, bm = blockIdx.y * BM;

    int scolS = ((l & 7) << 3) ^ ((l >> 3) << 3);
    int srowA = w * (BM / 4) + (l >> 3);
    int srowB = (w << 5) + (l >> 3);
    const short* pa = A  + (size_t)(bm + srowA) * K + scolS;
    const short* pb = Bt + (size_t)(bn + srowB) * K + scolS;
    short* dstA = As + w * (BM / 4) * 64;
    short* dstB = Bs + (w << 11);

    f32x4 acc[MI][4];
#pragma unroll
    for (int mi = 0; mi < MI; ++mi)
#pragma unroll
        for (int ni = 0; ni < 4; ++ni) acc[mi][ni] = (f32x4){0.f, 0.f, 0.f, 0.f};

    int swz = (lr & 7) << 3;
    int cur = 0;

    if (DBUF) {
#pragma unroll
        for (int i = 0; i < BM / 32; ++i)
            gload16(pa + (size_t)(i * 8) * K, dstA + (i << 9));
#pragma unroll
        for (int i = 0; i < 4; ++i)
            gload16(pb + (size_t)(i * 8) * K, dstB + (i << 9));
        __syncthreads();
    }

    for (int k0 = 0; k0 < K; k0 += 64) {
        if (DBUF) {
            if (k0 + 64 < K) {
                int nxt = cur ^ 1;
#pragma unroll
                for (int i = 0; i < BM / 32; ++i)
                    gload16(pa + (size_t)(i * 8) * K + k0 + 64, dstA + nxt * ASZ + (i << 9));
#pragma unroll
                for (int i = 0; i < 4; ++i)
                    gload16(pb + (size_t)(i * 8) * K + k0 + 64, dstB + nxt * BSZ + (i << 9));
            }
        } else {
            __syncthreads();
#pragma unroll
            for (int i = 0; i < BM / 32; ++i)
                gload16(pa + (size_t)(i * 8) * K + k0, dstA + (i << 9));
#pragma unroll
            for (int i = 0; i < 4; ++i)
                gload16(pb + (size_t)(i * 8) * K + k0, dstB + (i << 9));
            __syncthreads();
        }
        const short* curA = As + cur * ASZ;
        const short* curB = Bs + cur * BSZ;
#pragma unroll
        for (int ks = 0; ks < 2; ++ks) {
            s16x8 af[MI], bf[4];
#pragma unroll
            for (int mi = 0; mi < MI; ++mi) {
                int row = wr * (BM / 2) + (mi << 4) + lr;
                af[mi] = *reinterpret_cast<const s16x8*>(
                    &curA[(row << 6) + (((ks << 5) + lk8) ^ swz)]);
            }
#pragma unroll
            for (int ni = 0; ni < 4; ++ni) {
                int row = (wc << 6) + (ni << 4) + lr;
                bf[ni] = *reinterpret_cast<const s16x8*>(
                    &curB[(row << 6) + (((ks << 5) + lk8) ^ swz)]);
            }
            __builtin_amdgcn_s_setprio(1);
#pragma unroll
            for (int mi = 0; mi < MI; ++mi)
#pragma unroll
                for (int ni = 0; ni < 4; ++ni)
                    acc[mi][ni] = __builtin_amdgcn_mfma_f32_16x16x32_bf16(
                        af[mi], bf[ni], acc[mi][ni], 0, 0, 0);
            __builtin_amdgcn_s_setprio(0);
        }
        if (DBUF) {
            __syncthreads();
            cur ^= 1;
        }
    }

    float bv[4];
#pragma unroll
    for (int ni = 0; ni < 4; ++ni)
        bv[ni] = bias[bn + (wc << 6) + (ni << 4) + lr];

#pragma unroll
    for (int mi = 0; mi < MI; ++mi) {
#pragma unroll
        for (int ni = 0; ni < 4; ++ni) {
            int n = bn + (wc << 6) + (ni << 4) + lr;
#pragma unroll
            for (int r = 0; r < 4; ++r) {
                int m = bm + wr * (BM / 2) + (mi << 4) + r4 + r;
                float v = acc[mi][ni][r] + bv[ni];
                if (RELU) v = fmaxf(v, 0.0f);
                if (RES)  v += R[(size_t)m * N + n];
                if (OBF16) ((short*)Cv)[(size_t)m * N + n] = f2bf(v);
                else       ((float*)Cv)[(size_t)m * N + n] = v;
            }
        }
    }
}

// ------------------------------------- fused out-proj + residual + LN2 (dbuf)
__global__ __launch_bounds__(256) void oproj_ln_kernel(const short* __restrict__ A,
                                                       const short* __restrict__ Bt,
                                                       const float* __restrict__ bias,
                                                       const float* __restrict__ R,
                                                       float* __restrict__ x1,
                                                       short* __restrict__ h2,
                                                       const float* __restrict__ g,
                                                       const float* __restrict__ bb)
{
    constexpr int ASZ = 64 * 64;
    constexpr int BSZ = 256 * 64;
    __shared__ short As[2 * ASZ];
    __shared__ short Bs[2 * BSZ];

    int tid = threadIdx.x;
    int l   = tid & 63;
    int w   = tid >> 6;
    int lr  = l & 15;
    int lk8 = (l >> 4) << 3;
    int r4  = (l >> 4) << 2;
    int bm  = blockIdx.x * 64;

    int scolS = ((l & 7) << 3) ^ ((l >> 3) << 3);
    const short* pa = A  + (size_t)(bm + (w << 4) + (l >> 3)) * 256 + scolS;
    const short* pb = Bt + (size_t)((w << 6) + (l >> 3)) * 256 + scolS;
    short* dstA = As + (w << 10);
    short* dstB = Bs + (w << 12);

    f32x4 acc[16];
#pragma unroll
    for (int ni = 0; ni < 16; ++ni) acc[ni] = (f32x4){0.f, 0.f, 0.f, 0.f};

    int swz = (lr & 7) << 3;

#pragma unroll
    for (int i = 0; i < 2; ++i)
        gload16(pa + (size_t)(i * 8) * 256, dstA + (i << 9));
#pragma unroll
    for (int i = 0; i < 8; ++i)
        gload16(pb + (size_t)(i * 8) * 256, dstB + (i << 9));
    __syncthreads();

    int cur = 0;
    for (int k0 = 0; k0 < 256; k0 += 64) {
        if (k0 + 64 < 256) {
            int nxt = cur ^ 1;
#pragma unroll
            for (int i = 0; i < 2; ++i)
                gload16(pa + (size_t)(i * 8) * 256 + k0 + 64, dstA + nxt * ASZ + (i << 9));
#pragma unroll
            for (int i = 0; i < 8; ++i)
                gload16(pb + (size_t)(i * 8) * 256 + k0 + 64, dstB + nxt * BSZ + (i << 9));
        }
        const short* curA = As + cur * ASZ;
        const short* curB = Bs + cur * BSZ;
#pragma unroll
        for (int ks = 0; ks < 2; ++ks) {
            int arow = (w << 4) + lr;
            s16x8 af = *reinterpret_cast<const s16x8*>(
                &curA[(arow << 6) + (((ks << 5) + lk8) ^ swz)]);
            __builtin_amdgcn_s_setprio(1);
#pragma unroll
            for (int ni = 0; ni < 16; ++ni) {
                int row = (ni << 4) + lr;
                s16x8 bf = *reinterpret_cast<const s16x8*>(
                    &curB[(row << 6) + (((ks << 5) + lk8) ^ swz)]);
                acc[ni] = __builtin_amdgcn_mfma_f32_16x16x32_bf16(af, bf, acc[ni], 0, 0, 0);
            }
            __builtin_amdgcn_s_setprio(0);
        }
        __syncthreads();
        cur ^= 1;
    }

#pragma unroll
    for (int ni = 0; ni < 16; ++ni) {
        int n = (ni << 4) + lr;
        float bvx = bias[n];
#pragma unroll
        for (int r = 0; r < 4; ++r) {
            int m = bm + (w << 4) + r4 + r;
            acc[ni][r] += bvx + R[(size_t)m * 256 + n];
        }
    }
#pragma unroll
    for (int r = 0; r < 4; ++r) {
        float s = 0.0f;
#pragma unroll
        for (int ni = 0; ni < 16; ++ni) s += acc[ni][r];
        s += __shfl_xor(s, 1); s += __shfl_xor(s, 2);
        s += __shfl_xor(s, 4); s += __shfl_xor(s, 8);
        float mu = s * (1.0f / 256.0f);
        float q = 0.0f;
#pragma unroll
        for (int ni = 0; ni < 16; ++ni) {
            float d = acc[ni][r] - mu;
            q += d * d;
        }
        q += __shfl_xor(q, 1); q += __shfl_xor(q, 2);
        q += __shfl_xor(q, 4); q += __shfl_xor(q, 8);
        float rstd = rsqrtf(q * (1.0f / 256.0f) + 1e-5f);

        int m = bm + (w << 4) + r4 + r;
#pragma unroll
        for (int ni = 0; ni < 16; ++ni) {
            int n = (ni << 4) + lr;
            float v = acc[ni][r];
            x1[(size_t)m * 256 + n] = v;
            h2[(size_t)m * 256 + n] = f2bf((v - mu) * rstd * g[n] + bb[n]);
        }
    }
}

// ---------------------------------------------------------------- Attention
// 32x32x16 MFMA flash attention (r14 structure) + diagonal-tile skip:
// on the last kv-tile (kt == qt), tile jt is FULLY masked for wave w when
// jt > w (k >= qt*128+jt*32 > max q of the wave). Guard all per-jt work with
// jt < njt (njt = w+1 on the diagonal, else 4) — wave-uniform branch,
// compile-time jt indexing, bitwise-identical results (skipped tiles
// contributed exactly 0 / never won the running max).
__global__ __launch_bounds__(256, 2) void attn_kernel(const short* __restrict__ qk,
                                                      const short* __restrict__ vt,
                                                      short* __restrict__ o)
{
    constexpr int KSZ = 128 * 64;
    constexpr int VSZ = 64 * 128;
    __shared__ short Ks[2 * KSZ];
    __shared__ short Vs[2 * VSZ];

    int bid  = blockIdx.x;
    int xcd  = bid & 7;
    int j    = bid >> 3;
    int bhg  = j & 7;
    int qidx = j >> 3;
    int qt   = qidx < 4 ? qidx : 11 - qidx;   // {0,1,2,3,7,6,5,4}
    int bh   = (bhg << 3) | xcd;
    int b = bh >> 2, h = bh & 3;

    int tid = threadIdx.x;
    int l   = tid & 63;
    int w   = tid >> 6;
    int lq  = l & 31;
    int hg  = l >> 5;

    int krow0 = (w << 3) + (l >> 3);
    int kscol = ((l & 7) << 3) ^ (((l >> 3) & 7) << 3);
    const short* kgp = qk + (size_t)(b * 1024 + krow0) * 512 + 256 + h * 64 + kscol;
    short* dstK = Ks + (w << 3) * 64;
    int vrow0 = (w << 2) + (l >> 4);
    int vscol = ((l & 15) << 3) ^ ((vrow0 & 7) << 3);
    const short* vgp = vt + (size_t)((bh << 6) + vrow0) * 1024 + vscol;
    short* dstV = Vs + (w << 2) * 128;

    const short* qrow = qk + (size_t)(b * 1024 + qt * 128 + (w << 5) + lq) * 512
                        + h * 64 + (hg << 3);
    s16x8 qf[4];
#pragma unroll
    for (int ds = 0; ds < 4; ++ds)
        qf[ds] = *reinterpret_cast<const s16x8*>(qrow + 16 * ds);

#pragma unroll
    for (int i = 0; i < 4; ++i) {
        gload16(kgp + (size_t)(i * 32) * 512, dstK + i * 32 * 64);
        gload16(vgp + (size_t)(i * 16) * 1024, dstV + i * 16 * 128);
    }
    __syncthreads();

    float m = -1e30f, lsum = 0.0f;
    f32x16 oacc[2];
#pragma unroll
    for (int dt = 0; dt < 2; ++dt)
#pragma unroll
        for (int r = 0; r < 16; ++r) oacc[dt][r] = 0.0f;
    int qglob = qt * 128 + (w << 5) + lq;
    int cur = 0;
    int niter = qt + 1;

    for (int kt = 0; kt < niter; ++kt) {
        bool diag = (kt == niter - 1);
        int njt   = diag ? (w + 1) : 4;       // wave-uniform active-tile count

        if (kt + 1 < niter) {
            int nxt = cur ^ 1;
#pragma unroll
            for (int i = 0; i < 4; ++i) {
                gload16(kgp + (size_t)((kt + 1) * 128 + i * 32) * 512,
                        dstK + nxt * KSZ + i * 32 * 64);
                gload16(vgp + (size_t)(i * 16) * 1024 + (kt + 1) * 128,
                        dstV + nxt * VSZ + i * 16 * 128);
            }
        }

        // ---- S^T = K Q^T (active jt only) ----
        f32x16 sv[4];
#pragma unroll
        for (int jt = 0; jt < 4; ++jt)
#pragma unroll
            for (int r = 0; r < 16; ++r) sv[jt][r] = 0.0f;
        __builtin_amdgcn_s_setprio(1);
#pragma unroll
        for (int ds = 0; ds < 4; ++ds) {
#pragma unroll
            for (int jt = 0; jt < 4; ++jt) {
                if (jt < njt) {
                    int row = jt * 32 + lq;
                    s16x8 kf = *reinterpret_cast<const s16x8*>(
                        &Ks[cur * KSZ + (row << 6) + ((16 * ds + (hg << 3)) ^ ((row & 7) << 3))]);
                    sv[jt] = __builtin_amdgcn_mfma_f32_32x32x16_bf16(kf, qf[ds], sv[jt], 0, 0, 0);
                }
            }
        }
        __builtin_amdgcn_s_setprio(0);

        if (diag) {                  // causal mask on active diagonal tiles
#pragma unroll
            for (int jt = 0; jt < 4; ++jt) {
                if (jt < njt) {
#pragma unroll
                    for (int r = 0; r < 16; ++r) {
                        int kg = kt * 128 + jt * 32 + (r & 3) + ((r >> 2) << 3) + (hg << 2);
                        if (kg > qglob) sv[jt][r] = -1e30f;
                    }
                }
            }
        }

        // ---- prefetch V fragments for active jt (softmax covers latency) ----
        s16x8 vfr[16];               // [jj=2*jt+half][dt]
#pragma unroll
        for (int jj = 0; jj < 8; ++jj) {
            if (jj < 2 * njt) {
#pragma unroll
                for (int dt = 0; dt < 2; ++dt) {
                    int row = dt * 32 + lq;
                    int rs  = (row & 7) << 3;
                    vfr[jj * 2 + dt] = *reinterpret_cast<const s16x8*>(
                        &Vs[cur * VSZ + (row << 7) + ((16 * jj + (hg << 3)) ^ rs)]);
                }
            }
        }

        // ---- in-register online softmax + defer-max (THR=8, base-2) ----
        float rm = -1e30f;
#pragma unroll
        for (int jt = 0; jt < 4; ++jt)
            if (jt < njt)
#pragma unroll
                for (int r = 0; r < 16; ++r) rm = fmaxf(rm, sv[jt][r]);
        rm = fmaxf(rm, __shfl_xor(rm, 32));
        bool big = __any(rm > m + 8.0f);
        float fct = 1.0f;
        if (big) {
            float mn = fmaxf(m, rm);
            fct = exp2f(m - mn);
            m = mn;
        }
        float ps = 0.0f;
#pragma unroll
        for (int jt = 0; jt < 4; ++jt)
            if (jt < njt)
#pragma unroll
                for (int r = 0; r < 16; ++r) {
                    float p = exp2f(sv[jt][r] - m);
                    sv[jt][r] = p;
                    ps += p;
                }
        ps += __shfl_xor(ps, 32);
        lsum = lsum * fct + ps;

        if (big) {
#pragma unroll
            for (int r = 0; r < 16; ++r) {
                float f = __shfl(fct, (r & 3) + ((r >> 2) << 3) + (hg << 2));
                oacc[0][r] *= f;
                oacc[1][r] *= f;
            }
        }

        // ---- O += P V (active jt only; V already in registers) ----
#pragma unroll
        for (int jt = 0; jt < 4; ++jt) {
            if (jt < njt) {
                int x0 = cvt_pk_bf16(sv[jt][0],  sv[jt][1]);
                int x1v = cvt_pk_bf16(sv[jt][2],  sv[jt][3]);
                int y0 = cvt_pk_bf16(sv[jt][4],  sv[jt][5]);
                int y1 = cvt_pk_bf16(sv[jt][6],  sv[jt][7]);
                int z0 = cvt_pk_bf16(sv[jt][8],  sv[jt][9]);
                int z1 = cvt_pk_bf16(sv[jt][10], sv[jt][11]);
                int w0 = cvt_pk_bf16(sv[jt][12], sv[jt][13]);
                int w1 = cvt_pk_bf16(sv[jt][14], sv[jt][15]);
                swap32(x0, y0); swap32(x1v, y1);
                swap32(z0, w0); swap32(z1, w1);
                union { int i[4]; s16x8 v; } fA, fB;
                fA.i[0] = x0; fA.i[1] = x1v; fA.i[2] = y0; fA.i[3] = y1;
                fB.i[0] = z0; fB.i[1] = z1;  fB.i[2] = w0; fB.i[3] = w1;
                __builtin_amdgcn_s_setprio(1);
#pragma unroll
                for (int dt = 0; dt < 2; ++dt) {
                    oacc[dt] = __builtin_amdgcn_mfma_f32_32x32x16_bf16(
                        fA.v, vfr[(2 * jt) * 2 + dt], oacc[dt], 0, 0, 0);
                    oacc[dt] = __builtin_amdgcn_mfma_f32_32x32x16_bf16(
                        fB.v, vfr[(2 * jt + 1) * 2 + dt], oacc[dt], 0, 0, 0);
                }
                __builtin_amdgcn_s_setprio(0);
            }
        }

        if (kt + 1 < niter) {
            __syncthreads();
            cur ^= 1;
        }
    }

#pragma unroll
    for (int r = 0; r < 16; ++r) {
        int qr  = (r & 3) + ((r >> 2) << 3) + (hg << 2);
        float lv  = __shfl(lsum, qr);
        float inv = 1.0f / lv;
        int q = qt * 128 + (w << 5) + qr;
        short* orow = o + (size_t)(b * 1024 + q) * 256 + h * 64;
        orow[lq]      = f2bf(oacc[0][r] * inv);
        orow[32 + lq] = f2bf(oacc[1][r] * inv);
    }
}

// ---------------------------------------------------------------- launch
extern "C" void kernel_launch(void* const* d_in, const int* in_sizes, int n_in,
                              void* d_out, int out_size, void* d_ws, size_t ws_size,
                              hipStream_t stream)
{
    const float* x      = (const float*)d_in[0];
    const float* qkv_w  = (const float*)d_in[1];
    const float* qkv_b  = (const float*)d_in[2];
    const float* out_w  = (const float*)d_in[3];
    const float* out_b  = (const float*)d_in[4];
    const float* fc_w   = (const float*)d_in[5];
    const float* fc_b   = (const float*)d_in[6];
    const float* proj_w = (const float*)d_in[7];
    const float* proj_b = (const float*)d_in[8];
    const float* ln1_g  = (const float*)d_in[9];
    const float* ln1_b  = (const float*)d_in[10];
    const float* ln2_g  = (const float*)d_in[11];
    const float* ln2_b  = (const float*)d_in[12];
    float* out = (float*)d_out;

    short* ws = (short*)d_ws;
    short* wt_qkv  = ws;                     // [768][256]
    short* wt_out  = ws + 196608;            // [256][256]
    short* wt_fc   = ws + 262144;            // [1024][256]
    short* wt_proj = ws + 524288;            // [256][1024]
    short* bufA    = ws + 786432;            // [T,256] bf16 (h / o / h2)
    short* qk_buf  = ws + 4980736;           // [T,512] bf16 (q,k)
    short* vt_buf  = ws + 13369344;          // [64][64][1024] bf16 (V^T per bh)
    short* h3_buf  = ws + 4980736;           // [T,1024] overlays qk+vt (dead by MLP)

    dim3 blk(256);

    // 0. weight convert + LN1
    prep_kernel<<<dim3(4288), blk, 0, stream>>>(
        qkv_w, out_w, fc_w, proj_w, wt_qkv, wt_out, wt_fc, wt_proj,
        x, ln1_g, ln1_b, bufA);
    // 1. qkv = h @ qkv_w + qkv_b   -> qk_buf (q pre-scaled) + vt_buf
    qkv_gemm_kernel<128><<<dim3(6, 128), blk, 0, stream>>>(
        bufA, wt_qkv, qkv_b, qk_buf, vt_buf, 768, 256);
    // 2. o = attention(qk, vt)  — staged dbuf + V-prefetch + diagonal skip
    attn_kernel<<<dim3(512), blk, 0, stream>>>(qk_buf, vt_buf, bufA);
    // 3. x1 = x + o@out_w+out_b -> d_out ; h2 = LN2(x1) -> bufA
    oproj_ln_kernel<<<dim3(256), blk, 0, stream>>>(
        bufA, wt_out, out_b, x, out, bufA, ln2_g, ln2_b);
    // 4. h3 = relu(h2 @ fc_w + fc_b)
    mgemm_kernel<1, 0, 1, 128, 0><<<dim3(8, 128), blk, 0, stream>>>(
        bufA, wt_fc, fc_b, nullptr, h3_buf, 1024, 256);
    // 5. out = x1 + h3 @ proj_w + proj_b (in-place residual, dbuf)
    mgemm_kernel<0, 1, 0, 64, 1><<<dim3(2, 256), blk, 0, stream>>>(
        h3_buf, wt_proj, proj_b, out, out, 256, 1024);
}

// Round 16
// 118.483 us; speedup vs baseline: 1.0615x; 1.0615x over previous
//
#include <hip/hip_runtime.h>
#include <cstdint>

// Transformer block: B=16, S=1024, E=256, H=4, D=64. fp32 in/out, bf16 compute.
// T = B*S = 16384 tokens.  (r14 measured-best configuration: 119.0 us.)
//
//  0. prep  = wconv(all weights) + LN1(x)      -> ws (one kernel)
//  1. qkv   = h @ qkv_w + qkv_b         bf16   -> qk_buf [T,512] + vt_buf [BH,64,1024]
//             (q columns pre-scaled by 1/sqrt(D)*log2e)
//  2. o     = causal_attn(qk, vt)       bf16   -> bufA   (32x32 MFMA, QBLK=128,
//             KVBLK=128 dbuf staged, V-prefetch before softmax)
//  3. x1,h2 = fused(x + o@out_w+b, LN2) f32,bf16 -> d_out, bufA   (dbuf)
//  4. h3    = relu(h2 @ fc_w + b)       bf16   -> h3_buf
//  5. out   = x1 + h3 @ proj_w + b      fp32   -> d_out           (dbuf)
//
// Falsified variants (measured): fused MLP (r10/r11: 1 wave/SIMD latency-bound),
// no-LDS L2-direct attn (r13: +23 us), diagonal-tile skip (r15: +7 us, runtime
// guards defeat the scheduler), GEMM dbuf at 4-blocks/CU (r7: m132 trap),
// unpaired attn grid (r7: dispatch-mapping-dependent imbalance).

using f32x4  = __attribute__((ext_vector_type(4))) float;
using f32x16 = __attribute__((ext_vector_type(16))) float;
using s16x8  = __attribute__((ext_vector_type(8))) short;
using s16x4  = __attribute__((ext_vector_type(4))) short;

__device__ inline short f2bf(float f) {
    union { float f; unsigned u; } v{f};
    unsigned r = (v.u + 0x7FFFu + ((v.u >> 16) & 1u)) >> 16;   // RNE
    return (short)r;
}

__device__ inline int cvt_pk_bf16(float lo, float hi) {
    int d;
    asm("v_cvt_pk_bf16_f32 %0, %1, %2" : "=v"(d) : "v"(lo), "v"(hi));
    return d;
}
__device__ inline void swap32(int& a, int& b) {
    asm("v_permlane32_swap_b32 %0, %1" : "+v"(a), "+v"(b));
}
__device__ inline void swap16(int& a, int& b) {
    asm("v_permlane16_swap_b32 %0, %1" : "+v"(a), "+v"(b));
}

__device__ inline void gload16(const void* g, void* l) {
    __builtin_amdgcn_global_load_lds(
        (const __attribute__((address_space(1))) void*)g,
        (__attribute__((address_space(3))) void*)l, 16, 0, 0);
}

// ------------------------------------------------ prep: weight conv + LN1
__global__ __launch_bounds__(256) void prep_kernel(
    const float* __restrict__ qkv_w, const float* __restrict__ out_w,
    const float* __restrict__ fc_w,  const float* __restrict__ proj_w,
    short* __restrict__ wt_qkv, short* __restrict__ wt_out,
    short* __restrict__ wt_fc,  short* __restrict__ wt_proj,
    const float* __restrict__ x, const float* __restrict__ ln1_g,
    const float* __restrict__ ln1_b, short* __restrict__ hout)
{
    __shared__ short T[64][65];
    int id  = blockIdx.x;
    int tid = threadIdx.x;

    if (id < 192) {
        const float* W; short* Wt; int K, N, nt, kt;
        if (id < 48)       { W = qkv_w;  Wt = wt_qkv;  K = 256;  N = 768;  nt = id % 12;        kt = id / 12; }
        else if (id < 64)  { W = out_w;  Wt = wt_out;  K = 256;  N = 256;  nt = (id - 48) & 3;  kt = (id - 48) >> 2; }
        else if (id < 128) { W = fc_w;   Wt = wt_fc;   K = 256;  N = 1024; nt = (id - 64) & 15; kt = (id - 64) >> 4; }
        else               { W = proj_w; Wt = wt_proj; K = 1024; N = 256;  nt = (id - 128) & 3; kt = (id - 128) >> 2; }
        int n0 = nt * 64, k0 = kt * 64;
        int r = tid >> 2, c = (tid & 3) << 4;
        const float* src = W + (size_t)(k0 + r) * N + n0 + c;
#pragma unroll
        for (int u = 0; u < 4; ++u) {
            float4 v = *reinterpret_cast<const float4*>(src + u * 4);
            T[r][c + u * 4 + 0] = f2bf(v.x);
            T[r][c + u * 4 + 1] = f2bf(v.y);
            T[r][c + u * 4 + 2] = f2bf(v.z);
            T[r][c + u * 4 + 3] = f2bf(v.w);
        }
        __syncthreads();
        s16x8 o0, o1;
#pragma unroll
        for (int jj = 0; jj < 8; ++jj) { o0[jj] = T[c + jj][r]; o1[jj] = T[c + 8 + jj][r]; }
        short* dst = Wt + (size_t)(n0 + r) * K + k0 + c;
        *reinterpret_cast<s16x8*>(dst)     = o0;
        *reinterpret_cast<s16x8*>(dst + 8) = o1;
    } else {
        int lane = tid & 63;
        int row  = (id - 192) * 4 + (tid >> 6);
        const float* xr = x + (size_t)row * 256;
        float4 v = *reinterpret_cast<const float4*>(xr + lane * 4);
        float s = v.x + v.y + v.z + v.w;
#pragma unroll
        for (int o2 = 32; o2 >= 1; o2 >>= 1) s += __shfl_xor(s, o2);
        float mu = s * (1.0f / 256.0f);
        float dx = v.x - mu, dy = v.y - mu, dz = v.z - mu, dw = v.w - mu;
        float q = dx * dx + dy * dy + dz * dz + dw * dw;
#pragma unroll
        for (int o2 = 32; o2 >= 1; o2 >>= 1) q += __shfl_xor(q, o2);
        float rstd = rsqrtf(q * (1.0f / 256.0f) + 1e-5f);
        float4 gv = *reinterpret_cast<const float4*>(ln1_g + lane * 4);
        float4 bv = *reinterpret_cast<const float4*>(ln1_b + lane * 4);
        s16x4 ov;
        ov[0] = f2bf(dx * rstd * gv.x + bv.x);
        ov[1] = f2bf(dy * rstd * gv.y + bv.y);
        ov[2] = f2bf(dz * rstd * gv.z + bv.z);
        ov[3] = f2bf(dw * rstd * gv.w + bv.w);
        *reinterpret_cast<s16x4*>(hout + (size_t)row * 256 + lane * 4) = ov;
    }
}

// ---------------------------------------------------------------- MFMA GEMM (qkv)
template <int BM>
__global__ __launch_bounds__(256) void qkv_gemm_kernel(const short* __restrict__ A,
                                                       const short* __restrict__ Bt,
                                                       const float* __restrict__ bias,
                                                       short* __restrict__ qkout,
                                                       short* __restrict__ vt,
                                                       int N, int K)
{
    constexpr int MI = BM / 32;
    __shared__ short As[BM * 64];
    __shared__ short Bs[128 * 64];

    int tid = threadIdx.x;
    int l   = tid & 63;
    int w   = tid >> 6;
    int lr  = l & 15;
    int lk8 = (l >> 4) << 3;
    int r4  = (l >> 4) << 2;
    int wr  = w >> 1, wc = w & 1;
    int bn  = blockIdx.x * 128, bm = blockIdx.y * BM;

    int scolS = ((l & 7) << 3) ^ ((l >> 3) << 3);
    int srowA = w * (BM / 4) + (l >> 3);
    int srowB = (w << 5) + (l >> 3);
    const short* pa = A  + (size_t)(bm + srowA) * K + scolS;
    const short* pb = Bt + (size_t)(bn + srowB) * K + scolS;
    short* dstA = As + w * (BM / 4) * 64;
    short* dstB = Bs + (w << 11);

    f32x4 acc[MI][4];
#pragma unroll
    for (int mi = 0; mi < MI; ++mi)
#pragma unroll
        for (int ni = 0; ni < 4; ++ni) acc[mi][ni] = (f32x4){0.f, 0.f, 0.f, 0.f};

    int swz = (lr & 7) << 3;

    for (int k0 = 0; k0 < K; k0 += 64) {
        __syncthreads();
#pragma unroll
        for (int i = 0; i < BM / 32; ++i)
            gload16(pa + (size_t)(i * 8) * K + k0, dstA + (i << 9));
#pragma unroll
        for (int i = 0; i < 4; ++i)
            gload16(pb + (size_t)(i * 8) * K + k0, dstB + (i << 9));
        __syncthreads();

#pragma unroll
        for (int ks = 0; ks < 2; ++ks) {
            s16x8 af[MI], bf[4];
#pragma unroll
            for (int mi = 0; mi < MI; ++mi) {
                int row = wr * (BM / 2) + (mi << 4) + lr;
                af[mi] = *reinterpret_cast<const s16x8*>(
                    &As[(row << 6) + (((ks << 5) + lk8) ^ swz)]);
            }
#pragma unroll
            for (int ni = 0; ni < 4; ++ni) {
                int row = (wc << 6) + (ni << 4) + lr;
                bf[ni] = *reinterpret_cast<const s16x8*>(
                    &Bs[(row << 6) + (((ks << 5) + lk8) ^ swz)]);
            }
            __builtin_amdgcn_s_setprio(1);
#pragma unroll
            for (int mi = 0; mi < MI; ++mi)
#pragma unroll
                for (int ni = 0; ni < 4; ++ni)
                    acc[mi][ni] = __builtin_amdgcn_mfma_f32_16x16x32_bf16(
                        af[mi], bf[ni], acc[mi][ni], 0, 0, 0);
            __builtin_amdgcn_s_setprio(0);
        }
    }

    const float SCQ = 0.125f * 1.44269504088896f;   // 1/sqrt(D) * log2(e)
    float scale = (bn < 256) ? SCQ : 1.0f;          // block-uniform

    float bv[4];
#pragma unroll
    for (int ni = 0; ni < 4; ++ni)
        bv[ni] = bias[bn + (wc << 6) + (ni << 4) + lr];

#pragma unroll
    for (int mi = 0; mi < MI; ++mi) {
#pragma unroll
        for (int ni = 0; ni < 4; ++ni) {
            int n = bn + (wc << 6) + (ni << 4) + lr;
#pragma unroll
            for (int r = 0; r < 4; ++r) {
                int m = bm + wr * (BM / 2) + (mi << 4) + r4 + r;
                float v = acc[mi][ni][r] + bv[ni];
                if (bn < 512) {
                    qkout[(size_t)m * 512 + n] = f2bf(v * scale);
                } else {
                    int hh = (n - 512) >> 6, dd = (n - 512) & 63;
                    int bb = m >> 10, ss = m & 1023;
                    vt[(size_t)((((bb << 2) | hh) << 6) | dd) * 1024 + ss] = f2bf(v);
                }
            }
        }
    }
}

// ---------------------------------------------------------------- MFMA GEMM
template <int RELU, int RES, int OBF16, int BM, int DBUF>
__global__ __launch_bounds__(256) void mgemm_kernel(const short* __restrict__ A,
                                                    const short* __restrict__ Bt,
                                                    const float* __restrict__ bias,
                                                    const float* __restrict__ R,
                                                    void* __restrict__ Cv,
                                                    int N, int K)
{
    constexpr int MI  = BM / 32;
    constexpr int ASZ = BM * 64;
    constexpr int BSZ = 128 * 64;
    __shared__ short As[(1 + DBUF) * ASZ];
    __shared__ short Bs[(1 + DBUF) * BSZ];

    int tid = threadIdx.x;
    int l   = tid & 63;
    int w   = tid >> 6;
    int lr  = l & 15;
    int lk8 = (l >> 4) << 3;
    int r4  = (l >> 4) << 2;
    int wr  = w >> 1, wc = w & 1;
    int bn  = blockIdx.x * 128, bm = blockIdx.y * BM;

    int scolS = ((l & 7) << 3) ^ ((l >> 3) << 3);
    int srowA = w * (BM / 4) + (l >> 3);
    int srowB = (w << 5) + (l >> 3);
    const short* pa = A  + (size_t)(bm + srowA) * K + scolS;
    const short* pb = Bt + (size_t)(bn + srowB) * K + scolS;
    short* dstA = As + w * (BM / 4) * 64;
    short* dstB = Bs + (w << 11);

    f32x4 acc[MI][4];
#pragma unroll
    for (int mi = 0; mi < MI; ++mi)
#pragma unroll
        for (int ni = 0; ni < 4; ++ni) acc[mi][ni] = (f32x4){0.f, 0.f, 0.f, 0.f};

    int swz = (lr & 7) << 3;
    int cur = 0;

    if (DBUF) {
#pragma unroll
        for (int i = 0; i < BM / 32; ++i)
            gload16(pa + (size_t)(i * 8) * K, dstA + (i << 9));
#pragma unroll
        for (int i = 0; i < 4; ++i)
            gload16(pb + (size_t)(i * 8) * K, dstB + (i << 9));
        __syncthreads();
    }

    for (int k0 = 0; k0 < K; k0 += 64) {
        if (DBUF) {
            if (k0 + 64 < K) {
                int nxt = cur ^ 1;
#pragma unroll
                for (int i = 0; i < BM / 32; ++i)
                    gload16(pa + (size_t)(i * 8) * K + k0 + 64, dstA + nxt * ASZ + (i << 9));
#pragma unroll
                for (int i = 0; i < 4; ++i)
                    gload16(pb + (size_t)(i * 8) * K + k0 + 64, dstB + nxt * BSZ + (i << 9));
            }
        } else {
            __syncthreads();
#pragma unroll
            for (int i = 0; i < BM / 32; ++i)
                gload16(pa + (size_t)(i * 8) * K + k0, dstA + (i << 9));
#pragma unroll
            for (int i = 0; i < 4; ++i)
                gload16(pb + (size_t)(i * 8) * K + k0, dstB + (i << 9));
            __syncthreads();
        }
        const short* curA = As + cur * ASZ;
        const short* curB = Bs + cur * BSZ;
#pragma unroll
        for (int ks = 0; ks < 2; ++ks) {
            s16x8 af[MI], bf[4];
#pragma unroll
            for (int mi = 0; mi < MI; ++mi) {
                int row = wr * (BM / 2) + (mi << 4) + lr;
                af[mi] = *reinterpret_cast<const s16x8*>(
                    &curA[(row << 6) + (((ks << 5) + lk8) ^ swz)]);
            }
#pragma unroll
            for (int ni = 0; ni < 4; ++ni) {
                int row = (wc << 6) + (ni << 4) + lr;
                bf[ni] = *reinterpret_cast<const s16x8*>(
                    &curB[(row << 6) + (((ks << 5) + lk8) ^ swz)]);
            }
            __builtin_amdgcn_s_setprio(1);
#pragma unroll
            for (int mi = 0; mi < MI; ++mi)
#pragma unroll
                for (int ni = 0; ni < 4; ++ni)
                    acc[mi][ni] = __builtin_amdgcn_mfma_f32_16x16x32_bf16(
                        af[mi], bf[ni], acc[mi][ni], 0, 0, 0);
            __builtin_amdgcn_s_setprio(0);
        }
        if (DBUF) {
            __syncthreads();
            cur ^= 1;
        }
    }

    float bv[4];
#pragma unroll
    for (int ni = 0; ni < 4; ++ni)
        bv[ni] = bias[bn + (wc << 6) + (ni << 4) + lr];

#pragma unroll
    for (int mi = 0; mi < MI; ++mi) {
#pragma unroll
        for (int ni = 0; ni < 4; ++ni) {
            int n = bn + (wc << 6) + (ni << 4) + lr;
#pragma unroll
            for (int r = 0; r < 4; ++r) {
                int m = bm + wr * (BM / 2) + (mi << 4) + r4 + r;
                float v = acc[mi][ni][r] + bv[ni];
                if (RELU) v = fmaxf(v, 0.0f);
                if (RES)  v += R[(size_t)m * N + n];
                if (OBF16) ((short*)Cv)[(size_t)m * N + n] = f2bf(v);
                else       ((float*)Cv)[(size_t)m * N + n] = v;
            }
        }
    }
}

// ------------------------------------- fused out-proj + residual + LN2 (dbuf)
__global__ __launch_bounds__(256) void oproj_ln_kernel(const short* __restrict__ A,
                                                       const short* __restrict__ Bt,
                                                       const float* __restrict__ bias,
                                                       const float* __restrict__ R,
                                                       float* __restrict__ x1,
                                                       short* __restrict__ h2,
                                                       const float* __restrict__ g,
                                                       const float* __restrict__ bb)
{
    constexpr int ASZ = 64 * 64;
    constexpr int BSZ = 256 * 64;
    __shared__ short As[2 * ASZ];
    __shared__ short Bs[2 * BSZ];

    int tid = threadIdx.x;
    int l   = tid & 63;
    int w   = tid >> 6;
    int lr  = l & 15;
    int lk8 = (l >> 4) << 3;
    int r4  = (l >> 4) << 2;
    int bm  = blockIdx.x * 64;

    int scolS = ((l & 7) << 3) ^ ((l >> 3) << 3);
    const short* pa = A  + (size_t)(bm + (w << 4) + (l >> 3)) * 256 + scolS;
    const short* pb = Bt + (size_t)((w << 6) + (l >> 3)) * 256 + scolS;
    short* dstA = As + (w << 10);
    short* dstB = Bs + (w << 12);

    f32x4 acc[16];
#pragma unroll
    for (int ni = 0; ni < 16; ++ni) acc[ni] = (f32x4){0.f, 0.f, 0.f, 0.f};

    int swz = (lr & 7) << 3;

#pragma unroll
    for (int i = 0; i < 2; ++i)
        gload16(pa + (size_t)(i * 8) * 256, dstA + (i << 9));
#pragma unroll
    for (int i = 0; i < 8; ++i)
        gload16(pb + (size_t)(i * 8) * 256, dstB + (i << 9));
    __syncthreads();

    int cur = 0;
    for (int k0 = 0; k0 < 256; k0 += 64) {
        if (k0 + 64 < 256) {
            int nxt = cur ^ 1;
#pragma unroll
            for (int i = 0; i < 2; ++i)
                gload16(pa + (size_t)(i * 8) * 256 + k0 + 64, dstA + nxt * ASZ + (i << 9));
#pragma unroll
            for (int i = 0; i < 8; ++i)
                gload16(pb + (size_t)(i * 8) * 256 + k0 + 64, dstB + nxt * BSZ + (i << 9));
        }
        const short* curA = As + cur * ASZ;
        const short* curB = Bs + cur * BSZ;
#pragma unroll
        for (int ks = 0; ks < 2; ++ks) {
            int arow = (w << 4) + lr;
            s16x8 af = *reinterpret_cast<const s16x8*>(
                &curA[(arow << 6) + (((ks << 5) + lk8) ^ swz)]);
            __builtin_amdgcn_s_setprio(1);
#pragma unroll
            for (int ni = 0; ni < 16; ++ni) {
                int row = (ni << 4) + lr;
                s16x8 bf = *reinterpret_cast<const s16x8*>(
                    &curB[(row << 6) + (((ks << 5) + lk8) ^ swz)]);
                acc[ni] = __builtin_amdgcn_mfma_f32_16x16x32_bf16(af, bf, acc[ni], 0, 0, 0);
            }
            __builtin_amdgcn_s_setprio(0);
        }
        __syncthreads();
        cur ^= 1;
    }

#pragma unroll
    for (int ni = 0; ni < 16; ++ni) {
        int n = (ni << 4) + lr;
        float bvx = bias[n];
#pragma unroll
        for (int r = 0; r < 4; ++r) {
            int m = bm + (w << 4) + r4 + r;
            acc[ni][r] += bvx + R[(size_t)m * 256 + n];
        }
    }
#pragma unroll
    for (int r = 0; r < 4; ++r) {
        float s = 0.0f;
#pragma unroll
        for (int ni = 0; ni < 16; ++ni) s += acc[ni][r];
        s += __shfl_xor(s, 1); s += __shfl_xor(s, 2);
        s += __shfl_xor(s, 4); s += __shfl_xor(s, 8);
        float mu = s * (1.0f / 256.0f);
        float q = 0.0f;
#pragma unroll
        for (int ni = 0; ni < 16; ++ni) {
            float d = acc[ni][r] - mu;
            q += d * d;
        }
        q += __shfl_xor(q, 1); q += __shfl_xor(q, 2);
        q += __shfl_xor(q, 4); q += __shfl_xor(q, 8);
        float rstd = rsqrtf(q * (1.0f / 256.0f) + 1e-5f);

        int m = bm + (w << 4) + r4 + r;
#pragma unroll
        for (int ni = 0; ni < 16; ++ni) {
            int n = (ni << 4) + lr;
            float v = acc[ni][r];
            x1[(size_t)m * 256 + n] = v;
            h2[(size_t)m * 256 + n] = f2bf((v - mu) * rstd * g[n] + bb[n]);
        }
    }
}

// ---------------------------------------------------------------- Attention
// 32x32x16 MFMA flash attention (r14 measured-best). QBLK=128, KVBLK=128
// dbuf via global_load_lds. Q pre-scaled (base-2). V-fragments prefetched
// from LDS before the softmax phase (softmax VALU covers their latency).
__global__ __launch_bounds__(256, 2) void attn_kernel(const short* __restrict__ qk,
                                                      const short* __restrict__ vt,
                                                      short* __restrict__ o)
{
    constexpr int KSZ = 128 * 64;
    constexpr int VSZ = 64 * 128;
    __shared__ short Ks[2 * KSZ];
    __shared__ short Vs[2 * VSZ];

    int bid  = blockIdx.x;
    int xcd  = bid & 7;
    int j    = bid >> 3;
    int bhg  = j & 7;
    int qidx = j >> 3;
    int qt   = qidx < 4 ? qidx : 11 - qidx;   // {0,1,2,3,7,6,5,4}
    int bh   = (bhg << 3) | xcd;
    int b = bh >> 2, h = bh & 3;

    int tid = threadIdx.x;
    int l   = tid & 63;
    int w   = tid >> 6;
    int lq  = l & 31;
    int hg  = l >> 5;

    int krow0 = (w << 3) + (l >> 3);
    int kscol = ((l & 7) << 3) ^ (((l >> 3) & 7) << 3);
    const short* kgp = qk + (size_t)(b * 1024 + krow0) * 512 + 256 + h * 64 + kscol;
    short* dstK = Ks + (w << 3) * 64;
    int vrow0 = (w << 2) + (l >> 4);
    int vscol = ((l & 15) << 3) ^ ((vrow0 & 7) << 3);
    const short* vgp = vt + (size_t)((bh << 6) + vrow0) * 1024 + vscol;
    short* dstV = Vs + (w << 2) * 128;

    const short* qrow = qk + (size_t)(b * 1024 + qt * 128 + (w << 5) + lq) * 512
                        + h * 64 + (hg << 3);
    s16x8 qf[4];
#pragma unroll
    for (int ds = 0; ds < 4; ++ds)
        qf[ds] = *reinterpret_cast<const s16x8*>(qrow + 16 * ds);

#pragma unroll
    for (int i = 0; i < 4; ++i) {
        gload16(kgp + (size_t)(i * 32) * 512, dstK + i * 32 * 64);
        gload16(vgp + (size_t)(i * 16) * 1024, dstV + i * 16 * 128);
    }
    __syncthreads();

    float m = -1e30f, lsum = 0.0f;
    f32x16 oacc[2];
#pragma unroll
    for (int dt = 0; dt < 2; ++dt)
#pragma unroll
        for (int r = 0; r < 16; ++r) oacc[dt][r] = 0.0f;
    int qglob = qt * 128 + (w << 5) + lq;
    int cur = 0;
    int niter = qt + 1;

    for (int kt = 0; kt < niter; ++kt) {
        if (kt + 1 < niter) {
            int nxt = cur ^ 1;
#pragma unroll
            for (int i = 0; i < 4; ++i) {
                gload16(kgp + (size_t)((kt + 1) * 128 + i * 32) * 512,
                        dstK + nxt * KSZ + i * 32 * 64);
                gload16(vgp + (size_t)(i * 16) * 1024 + (kt + 1) * 128,
                        dstV + nxt * VSZ + i * 16 * 128);
            }
        }

        // ---- S^T = K Q^T ----
        f32x16 sv[4];
#pragma unroll
        for (int jt = 0; jt < 4; ++jt)
#pragma unroll
            for (int r = 0; r < 16; ++r) sv[jt][r] = 0.0f;
        __builtin_amdgcn_s_setprio(1);
#pragma unroll
        for (int ds = 0; ds < 4; ++ds) {
#pragma unroll
            for (int jt = 0; jt < 4; ++jt) {
                int row = jt * 32 + lq;
                s16x8 kf = *reinterpret_cast<const s16x8*>(
                    &Ks[cur * KSZ + (row << 6) + ((16 * ds + (hg << 3)) ^ ((row & 7) << 3))]);
                sv[jt] = __builtin_amdgcn_mfma_f32_32x32x16_bf16(kf, qf[ds], sv[jt], 0, 0, 0);
            }
        }
        __builtin_amdgcn_s_setprio(0);

        if (kt == niter - 1) {       // causal mask on diagonal tile
#pragma unroll
            for (int jt = 0; jt < 4; ++jt)
#pragma unroll
                for (int r = 0; r < 16; ++r) {
                    int kg = kt * 128 + jt * 32 + (r & 3) + ((r >> 2) << 3) + (hg << 2);
                    if (kg > qglob) sv[jt][r] = -1e30f;
                }
        }

        // ---- prefetch ALL V fragments (depend only on kt; softmax covers) ----
        s16x8 vfr[16];               // [jj=2*jt+half][dt]
#pragma unroll
        for (int jj = 0; jj < 8; ++jj) {
#pragma unroll
            for (int dt = 0; dt < 2; ++dt) {
                int row = dt * 32 + lq;
                int rs  = (row & 7) << 3;
                vfr[jj * 2 + dt] = *reinterpret_cast<const s16x8*>(
                    &Vs[cur * VSZ + (row << 7) + ((16 * jj + (hg << 3)) ^ rs)]);
            }
        }

        // ---- in-register online softmax + defer-max (THR=8, base-2) ----
        float rm = -1e30f;
#pragma unroll
        for (int jt = 0; jt < 4; ++jt)
#pragma unroll
            for (int r = 0; r < 16; ++r) rm = fmaxf(rm, sv[jt][r]);
        rm = fmaxf(rm, __shfl_xor(rm, 32));
        bool big = __any(rm > m + 8.0f);
        float fct = 1.0f;
        if (big) {
            float mn = fmaxf(m, rm);
            fct = exp2f(m - mn);
            m = mn;
        }
        float ps = 0.0f;
#pragma unroll
        for (int jt = 0; jt < 4; ++jt)
#pragma unroll
            for (int r = 0; r < 16; ++r) {
                float p = exp2f(sv[jt][r] - m);
                sv[jt][r] = p;
                ps += p;
            }
        ps += __shfl_xor(ps, 32);
        lsum = lsum * fct + ps;

        if (big) {
#pragma unroll
            for (int r = 0; r < 16; ++r) {
                float f = __shfl(fct, (r & 3) + ((r >> 2) << 3) + (hg << 2));
                oacc[0][r] *= f;
                oacc[1][r] *= f;
            }
        }

        // ---- O += P V (V already in registers) ----
#pragma unroll
        for (int jt = 0; jt < 4; ++jt) {
            int x0 = cvt_pk_bf16(sv[jt][0],  sv[jt][1]);
            int x1v = cvt_pk_bf16(sv[jt][2],  sv[jt][3]);
            int y0 = cvt_pk_bf16(sv[jt][4],  sv[jt][5]);
            int y1 = cvt_pk_bf16(sv[jt][6],  sv[jt][7]);
            int z0 = cvt_pk_bf16(sv[jt][8],  sv[jt][9]);
            int z1 = cvt_pk_bf16(sv[jt][10], sv[jt][11]);
            int w0 = cvt_pk_bf16(sv[jt][12], sv[jt][13]);
            int w1 = cvt_pk_bf16(sv[jt][14], sv[jt][15]);
            swap32(x0, y0); swap32(x1v, y1);
            swap32(z0, w0); swap32(z1, w1);
            union { int i[4]; s16x8 v; } fA, fB;
            fA.i[0] = x0; fA.i[1] = x1v; fA.i[2] = y0; fA.i[3] = y1;
            fB.i[0] = z0; fB.i[1] = z1;  fB.i[2] = w0; fB.i[3] = w1;
            __builtin_amdgcn_s_setprio(1);
#pragma unroll
            for (int dt = 0; dt < 2; ++dt) {
                oacc[dt] = __builtin_amdgcn_mfma_f32_32x32x16_bf16(
                    fA.v, vfr[(2 * jt) * 2 + dt], oacc[dt], 0, 0, 0);
                oacc[dt] = __builtin_amdgcn_mfma_f32_32x32x16_bf16(
                    fB.v, vfr[(2 * jt + 1) * 2 + dt], oacc[dt], 0, 0, 0);
            }
            __builtin_amdgcn_s_setprio(0);
        }

        if (kt + 1 < niter) {
            __syncthreads();
            cur ^= 1;
        }
    }

#pragma unroll
    for (int r = 0; r < 16; ++r) {
        int qr  = (r & 3) + ((r >> 2) << 3) + (hg << 2);
        float lv  = __shfl(lsum, qr);
        float inv = 1.0f / lv;
        int q = qt * 128 + (w << 5) + qr;
        short* orow = o + (size_t)(b * 1024 + q) * 256 + h * 64;
        orow[lq]      = f2bf(oacc[0][r] * inv);
        orow[32 + lq] = f2bf(oacc[1][r] * inv);
    }
}

// ---------------------------------------------------------------- launch
extern "C" void kernel_launch(void* const* d_in, const int* in_sizes, int n_in,
                              void* d_out, int out_size, void* d_ws, size_t ws_size,
                              hipStream_t stream)
{
    const float* x      = (const float*)d_in[0];
    const float* qkv_w  = (const float*)d_in[1];
    const float* qkv_b  = (const float*)d_in[2];
    const float* out_w  = (const float*)d_in[3];
    const float* out_b  = (const float*)d_in[4];
    const float* fc_w   = (const float*)d_in[5];
    const float* fc_b   = (const float*)d_in[6];
    const float* proj_w = (const float*)d_in[7];
    const float* proj_b = (const float*)d_in[8];
    const float* ln1_g  = (const float*)d_in[9];
    const float* ln1_b  = (const float*)d_in[10];
    const float* ln2_g  = (const float*)d_in[11];
    const float* ln2_b  = (const float*)d_in[12];
    float* out = (float*)d_out;

    short* ws = (short*)d_ws;
    short* wt_qkv  = ws;                     // [768][256]
    short* wt_out  = ws + 196608;            // [256][256]
    short* wt_fc   = ws + 262144;            // [1024][256]
    short* wt_proj = ws + 524288;            // [256][1024]
    short* bufA    = ws + 786432;            // [T,256] bf16 (h / o / h2)
    short* qk_buf  = ws + 4980736;           // [T,512] bf16 (q,k)
    short* vt_buf  = ws + 13369344;          // [64][64][1024] bf16 (V^T per bh)
    short* h3_buf  = ws + 4980736;           // [T,1024] overlays qk+vt (dead by MLP)

    dim3 blk(256);

    // 0. weight convert + LN1
    prep_kernel<<<dim3(4288), blk, 0, stream>>>(
        qkv_w, out_w, fc_w, proj_w, wt_qkv, wt_out, wt_fc, wt_proj,
        x, ln1_g, ln1_b, bufA);
    // 1. qkv = h @ qkv_w + qkv_b   -> qk_buf (q pre-scaled) + vt_buf
    qkv_gemm_kernel<128><<<dim3(6, 128), blk, 0, stream>>>(
        bufA, wt_qkv, qkv_b, qk_buf, vt_buf, 768, 256);
    // 2. o = attention(qk, vt)  — staged dbuf (r12) + V-prefetch
    attn_kernel<<<dim3(512), blk, 0, stream>>>(qk_buf, vt_buf, bufA);
    // 3. x1 = x + o@out_w+out_b -> d_out ; h2 = LN2(x1) -> bufA
    oproj_ln_kernel<<<dim3(256), blk, 0, stream>>>(
        bufA, wt_out, out_b, x, out, bufA, ln2_g, ln2_b);
    // 4. h3 = relu(h2 @ fc_w + fc_b)
    mgemm_kernel<1, 0, 1, 128, 0><<<dim3(8, 128), blk, 0, stream>>>(
        bufA, wt_fc, fc_b, nullptr, h3_buf, 1024, 256);
    // 5. out = x1 + h3 @ proj_w + proj_b (in-place residual, dbuf)
    mgemm_kernel<0, 1, 0, 64, 1><<<dim3(2, 256), blk, 0, stream>>>(
        h3_buf, wt_proj, proj_b, out, out, 256, 1024);
}